// Round 9
// baseline (128.363 us; speedup 1.0000x reference)
//
#include <hip/hip_runtime.h>
#include <hip/hip_bf16.h>

typedef __bf16 bf16x8 __attribute__((ext_vector_type(8)));
typedef unsigned short u16x8 __attribute__((ext_vector_type(8)));
typedef unsigned short u16x4 __attribute__((ext_vector_type(4)));
typedef float f32x4 __attribute__((ext_vector_type(4)));
typedef unsigned short u16;

constexpr int DIMc = 256, Tt = 2048, Kk = 1024, Dd = 64;

// ws layout (u16 offsets). Rows 16B-aligned for direct global fragment loads:
// WinT[64][264] @0 ; CbX[1024][72] @16896 (row k = -2*c_k) ; WoX[256][72] @90624 ;
// cnorm fp32[1024] @ float-index 54528. All L2-resident (~215 KB).
#define WS_WINT 0
#define WS_CBX  16896
#define WS_WOX  90624
#define WS_CN_F 54528

__device__ __forceinline__ u16 f2b(float f) {   // RNE float->bf16 bits
  unsigned u = __float_as_uint(f);
  return (u16)((u + 0x7FFFu + ((u >> 16) & 1u)) >> 16);
}
__device__ __forceinline__ f32x4 mfma16(u16x8 a, u16x8 b, f32x4 c) {
  return __builtin_amdgcn_mfma_f32_16x16x32_bf16(
      __builtin_bit_cast(bf16x8, a), __builtin_bit_cast(bf16x8, b), c, 0, 0, 0);
}

// Coalesced WRITES (consecutive threads -> consecutive addresses); gather reads.
__global__ void nsvq_prep(const float* __restrict__ cb, const float* __restrict__ Win,
                          const float* __restrict__ Wout, u16* __restrict__ wsu) {
  const int g = blockIdx.x * 256 + threadIdx.x;   // 32 blocks -> 8192 threads
  for (int i = g; i < 16384; i += 8192) {          // WinT: [d][c] <- Win[c][d]
    int d = i >> 8, c = i & 255;
    wsu[WS_WINT + d * 264 + c] = f2b(Win[c * 64 + d]);   // write coalesced
  }
  for (int i = g; i < 65536; i += 8192) {          // CbX: -2*cb, row-padded
    int k = i >> 6, d = i & 63;
    wsu[WS_CBX + k * 72 + d] = f2b(-2.f * cb[i]);        // read+write coalesced
  }
  for (int i = g; i < 16384; i += 8192) {          // WoX: [c][d] <- Wout[d][c]
    int c = i >> 6, d = i & 63;
    wsu[WS_WOX + c * 72 + d] = f2b(Wout[d * 256 + c]);   // write coalesced
  }
  if (g < 1024) {                                  // cnorm (fp32)
    const float4* cr = (const float4*)(cb + (size_t)g * 64);
    float cn = 0.f;
    #pragma unroll
    for (int q = 0; q < 16; ++q) {
      float4 v = cr[q];
      cn = fmaf(v.x, v.x, fmaf(v.y, v.y, fmaf(v.z, v.z, fmaf(v.w, v.w, cn))));
    }
    ((float*)wsu)[WS_CN_F + g] = cn;
  }
}

// Block = 64 tokens, 4 waves; wave w owns tokens [w*16, w*16+16) end-to-end.
// Weights/codebook fragments loaded DIRECTLY global->VGPR (L2-hot). 3 barriers.
__global__ __launch_bounds__(256, 2) void nsvq_main(
    const float* __restrict__ in, const float* __restrict__ rnd,
    const float* __restrict__ bin, const float* __restrict__ bout,
    const u16* __restrict__ wsu, const float* __restrict__ cnorm,
    float* __restrict__ out) {
  __shared__ u16 InT[64 * 256];     // 32 KB, [t][c] bf16, 16B-block XOR swizzle
  __shared__ u16 Xt[64 * 64];       // 8 KB, [t][d] bf16, swizzled
  __shared__ float mnp[4][64];      // per-wave code-slice mins

  const int tid  = threadIdx.x;
  const int lane = tid & 63;
  const int w    = tid >> 6;                   // 0..3
  const int quad = lane >> 4, col = lane & 15;
  const int b  = blockIdx.x >> 5;              // 512 blocks: 16 b x 32 tiles
  const int t0 = (blockIdx.x & 31) << 6;
  const int myt = w * 16 + col;                // own token row (0..63)

  // ---- stage InT (fp32->bf16, transpose, packed b128 writes) ----
  {
    const float* ib = in + (size_t)b * DIMc * Tt + t0 + lane;   // lane = t
    #pragma unroll
    for (int it = 0; it < 8; ++it) {
      int c0 = w * 64 + it * 8;
      u16x8 pk;
      #pragma unroll
      for (int j = 0; j < 8; ++j) pk[j] = f2b(ib[(size_t)(c0 + j) * Tt]);
      *(u16x8*)(InT + lane * 256 + (((c0 >> 3) ^ (lane & 7)) << 3)) = pk;
    }
  }
  __syncthreads();   // [barrier 1] InT ready

  // ---- encode: X^T = WinT · InT ; A-fragments from global (L2) ----
  f32x4 acc[4];
  {
    u16x8 Bf[8];
    #pragma unroll
    for (int kt = 0; kt < 8; ++kt)
      Bf[kt] = *(const u16x8*)(InT + myt * 256 + (((kt * 4 + quad) ^ (myt & 7)) << 3));
    #pragma unroll
    for (int mt = 0; mt < 4; ++mt) {
      acc[mt] = *(const f32x4*)(bin + mt * 16 + quad * 4);
      const u16* ar = wsu + WS_WINT + (mt * 16 + col) * 264 + quad * 8;
      #pragma unroll
      for (int kt = 0; kt < 8; ++kt) {
        u16x8 A = *(const u16x8*)(ar + kt * 32);
        acc[mt] = mfma16(A, Bf[kt], acc[mt]);
      }
    }
  }
  float x2v = 0.f;
  #pragma unroll
  for (int mt = 0; mt < 4; ++mt) {
    u16x4 pk;
    #pragma unroll
    for (int r = 0; r < 4; ++r) { x2v = fmaf(acc[mt][r], acc[mt][r], x2v); pk[r] = f2b(acc[mt][r]); }
    int bk = mt * 2 + (quad >> 1);
    *(u16x4*)(Xt + myt * 64 + ((bk ^ (myt & 7)) << 3) + (quad & 1) * 4) = pk;
  }
  x2v += __shfl_xor(x2v, 16);
  x2v += __shfl_xor(x2v, 32);                  // x2 of token myt in all lanes
  __syncthreads();   // [barrier 2] Xt complete (cross-wave B-fragments next)

  // ---- prefetch rnd for own token (hidden under distance loop) ----
  const float* rp = rnd + ((size_t)(b * Tt) + t0 + myt) * Dd;
  f32x4 rv[4];
  #pragma unroll
  for (int mt = 0; mt < 4; ++mt) rv[mt] = *(const f32x4*)(rp + mt * 16 + quad * 4);

  // ---- distances: wave w scans codes {it-slice}; A-frags direct from global ----
  u16x8 Xa[4], Xb[4];
  #pragma unroll
  for (int nt = 0; nt < 4; ++nt) {
    int tr = nt * 16 + col;
    Xa[nt] = *(const u16x8*)(Xt + tr * 64 + ((quad ^ (tr & 7)) << 3));
    Xb[nt] = *(const u16x8*)(Xt + tr * 64 + (((4 + quad) ^ (tr & 7)) << 3));
  }
  float minv[4] = {3.4e38f, 3.4e38f, 3.4e38f, 3.4e38f};
  {
    // it = 0..15: code = (it>>1)*128 + w*32 + (it&1)*16 + col  (16 codes/iter)
    const u16* cb0 = wsu + WS_CBX + (w * 32 + col) * 72 + quad * 8;
    const float* cn0 = cnorm + w * 32 + quad * 4;
    u16x8 A0 = *(const u16x8*)(cb0);
    u16x8 A1 = *(const u16x8*)(cb0 + 32);
    f32x4 cn = *(const f32x4*)(cn0);
    #pragma unroll
    for (int it = 0; it < 16; ++it) {
      u16x8 nA0, nA1; f32x4 ncn;
      if (it < 15) {                           // software prefetch next slice
        int nx = it + 1;
        int off = ((nx >> 1) << 7) + ((nx & 1) << 4);   // code offset
        nA0 = *(const u16x8*)(cb0 + off * 72);
        nA1 = *(const u16x8*)(cb0 + off * 72 + 32);
        ncn = *(const f32x4*)(cn0 + off);
      }
      #pragma unroll
      for (int nt = 0; nt < 4; ++nt) {
        f32x4 a = cn;                          // dist = cnorm + (-2c)·x
        a = mfma16(A0, Xa[nt], a);
        a = mfma16(A1, Xb[nt], a);
        #pragma unroll
        for (int r = 0; r < 4; ++r) minv[nt] = fminf(minv[nt], a[r]);
      }
      A0 = nA0; A1 = nA1; cn = ncn;
    }
  }
  #pragma unroll
  for (int nt = 0; nt < 4; ++nt) {
    float m = minv[nt];
    m = fminf(m, __shfl_xor(m, 16));
    m = fminf(m, __shfl_xor(m, 32));
    mnp[w][nt * 16 + col] = m;                 // all quads write same value
  }
  __syncthreads();   // [barrier 3] mnp ready; all Xt reads done

  // ---- scale + q-update fully in registers -> own Xt rows ----
  float rr2v = 0.f;
  #pragma unroll
  for (int mt = 0; mt < 4; ++mt)
    #pragma unroll
    for (int r = 0; r < 4; ++r) rr2v = fmaf(rv[mt][r], rv[mt][r], rr2v);
  rr2v += __shfl_xor(rr2v, 16);
  rr2v += __shfl_xor(rr2v, 32);
  float mv = fminf(fminf(mnp[0][myt], mnp[1][myt]), fminf(mnp[2][myt], mnp[3][myt]));
  float r2  = fmaxf(x2v + mv, 0.f);            // ||x - hard||^2
  float scv = sqrtf(r2) / (sqrtf(rr2v) + 1e-12f);
  #pragma unroll
  for (int mt = 0; mt < 4; ++mt) {             // q = x + sc*rnd -> Xt (bf16)
    u16x4 pk;
    #pragma unroll
    for (int r = 0; r < 4; ++r) pk[r] = f2b(fmaf(scv, rv[mt][r], acc[mt][r]));
    int bk = mt * 2 + (quad >> 1);
    *(u16x4*)(Xt + myt * 64 + ((bk ^ (myt & 7)) << 3) + (quad & 1) * 4) = pk;
  }
  // own-wave Xt rows only -> no barrier (lgkmcnt ordering within wave)

  // ---- decode: out = WoX · q + b_out ; A-frags direct from global ----
  u16x8 Q0 = *(const u16x8*)(Xt + myt * 64 + ((quad ^ (myt & 7)) << 3));
  u16x8 Q1 = *(const u16x8*)(Xt + myt * 64 + (((4 + quad) ^ (myt & 7)) << 3));
  float* ob0 = out + (size_t)b * DIMc * Tt + t0 + myt;
  #pragma unroll
  for (int mt = 0; mt < 16; ++mt) {
    f32x4 a = *(const f32x4*)(bout + mt * 16 + quad * 4);
    const u16* ar = wsu + WS_WOX + (mt * 16 + col) * 72 + quad * 8;
    u16x8 A0 = *(const u16x8*)(ar);
    u16x8 A1 = *(const u16x8*)(ar + 32);
    a = mfma16(A0, Q0, a);
    a = mfma16(A1, Q1, a);
    #pragma unroll
    for (int r = 0; r < 4; ++r) ob0[(size_t)(mt * 16 + quad * 4 + r) * Tt] = a[r];
  }
}

extern "C" void kernel_launch(void* const* d_in, const int* in_sizes, int n_in,
                              void* d_out, int out_size, void* d_ws, size_t ws_size,
                              hipStream_t stream) {
  const float *in = nullptr, *cb = nullptr, *rnd = nullptr, *bin = nullptr, *bout = nullptr;
  const float* w16[2] = {nullptr, nullptr}; int nw = 0;
  for (int i = 0; i < n_in; ++i) {
    switch (in_sizes[i]) {
      case 8388608: in  = (const float*)d_in[i]; break;
      case 65536:   cb  = (const float*)d_in[i]; break;
      case 2097152: rnd = (const float*)d_in[i]; break;
      case 64:      bin = (const float*)d_in[i]; break;
      case 256:     bout= (const float*)d_in[i]; break;
      case 16384:   if (nw < 2) w16[nw++] = (const float*)d_in[i]; break;
      default: break;
    }
  }
  if (!in)  in  = (const float*)d_in[0];
  if (!cb)  cb  = (const float*)d_in[1];
  if (nw < 2) { w16[0] = (const float*)d_in[2]; w16[1] = (const float*)d_in[4]; }
  if (!bin) bin = (const float*)d_in[3];
  if (!bout) bout = (const float*)d_in[5];
  if (!rnd) rnd = (const float*)d_in[6];

  u16* wsu = (u16*)d_ws;
  const float* cnorm = (const float*)d_ws + WS_CN_F;
  float* outp = (float*)d_out;

  nsvq_prep<<<32, 256, 0, stream>>>(cb, w16[0], w16[1], wsu);
  nsvq_main<<<512, 256, 0, stream>>>(in, rnd, bin, bout, wsu, cnorm, outp);
}